// Round 1
// baseline (285.713 us; speedup 1.0000x reference)
//
#include <hip/hip_runtime.h>

// Block-diagonal linear: y[b, n*64+d] = sum_s x[b, n*64+s] * W[n][d][s]
// B = 8192 rows, IN = OUT = 4096, NB = 64 blocks of 64x64.
// Memory-bound (~257 MiB @ 6.3 TB/s ~= 43 us floor). bf16 MFMA so compute is free.

#define NBLK 64
#define BLKD 64
#define INF 4096
#define NROWS 8192
#define CHUNK_ROWS 64   // 4 waves x 16 rows
#define CHUNKS 4        // row-chunks per workgroup

typedef short bf16x8 __attribute__((ext_vector_type(8)));
typedef float f32x4 __attribute__((ext_vector_type(4)));

__device__ inline unsigned short bf_rne(float f) {
    union { float f; unsigned u; } v;
    v.f = f;
    unsigned u = v.u;
    u += 0x7fffu + ((u >> 16) & 1u);   // round-to-nearest-even to bf16
    return (unsigned short)(u >> 16);
}

__device__ inline bf16x8 cvt8(float4 a, float4 b) {
    bf16x8 r;
    r[0] = (short)bf_rne(a.x);
    r[1] = (short)bf_rne(a.y);
    r[2] = (short)bf_rne(a.z);
    r[3] = (short)bf_rne(a.w);
    r[4] = (short)bf_rne(b.x);
    r[5] = (short)bf_rne(b.y);
    r[6] = (short)bf_rne(b.z);
    r[7] = (short)bf_rne(b.w);
    return r;
}

__global__ __launch_bounds__(256, 4) void StructuredLinearBlocks_kernel(
        const float* __restrict__ x, const float* __restrict__ w,
        float* __restrict__ y) {
    const int n    = blockIdx.y;          // which diagonal block
    const int tid  = threadIdx.x;
    const int wid  = tid >> 6;            // wave 0..3
    const int lane = tid & 63;
    const int l15  = lane & 15;
    const int lhi  = lane >> 4;           // 0..3

    // --- B fragments: B[k][col] = W[n][col][k]; W row-major [d][s] is exactly
    // the "B^T input" layout, so lanes read 8 consecutive fp32 per fragment.
    // 4 col-tiles (16 cols each) x 2 K-halves (K=32 each) -> kept in registers.
    const float* wn = w + n * (BLKD * BLKD);
    bf16x8 bfrag[4][2];
#pragma unroll
    for (int t = 0; t < 4; ++t) {
#pragma unroll
        for (int h = 0; h < 2; ++h) {
            const float* p = wn + (t * 16 + l15) * BLKD + h * 32 + lhi * 8;
            float4 lo = *(const float4*)p;
            float4 hi = *(const float4*)(p + 4);
            bfrag[t][h] = cvt8(lo, hi);
        }
    }

    const int row_wg = blockIdx.x * (CHUNK_ROWS * CHUNKS);
#pragma unroll
    for (int c = 0; c < CHUNKS; ++c) {
        const int r0 = row_wg + c * CHUNK_ROWS + wid * 16;

        // A fragments: lane reads 8 consecutive fp32 from its row, per K-half.
        const float* xp = x + (r0 + l15) * INF + n * BLKD;
        float4 a0 = *(const float4*)(xp + lhi * 8);
        float4 a1 = *(const float4*)(xp + lhi * 8 + 4);
        float4 a2 = *(const float4*)(xp + 32 + lhi * 8);
        float4 a3 = *(const float4*)(xp + 32 + lhi * 8 + 4);
        bf16x8 af0 = cvt8(a0, a1);
        bf16x8 af1 = cvt8(a2, a3);

        f32x4 acc[4];
#pragma unroll
        for (int t = 0; t < 4; ++t) {
            acc[t] = (f32x4){0.f, 0.f, 0.f, 0.f};
            acc[t] = __builtin_amdgcn_mfma_f32_16x16x32_bf16(af0, bfrag[t][0], acc[t], 0, 0, 0);
            acc[t] = __builtin_amdgcn_mfma_f32_16x16x32_bf16(af1, bfrag[t][1], acc[t], 0, 0, 0);
        }

        // C/D layout (verified m89/m91): col = lane&15, row = (lane>>4)*4 + reg.
        float* yp = y + (r0 + lhi * 4) * INF + n * BLKD + l15;
#pragma unroll
        for (int t = 0; t < 4; ++t) {
#pragma unroll
            for (int j = 0; j < 4; ++j) {
                yp[j * INF + t * 16] = acc[t][j];
            }
        }
    }
}

extern "C" void kernel_launch(void* const* d_in, const int* in_sizes, int n_in,
                              void* d_out, int out_size, void* d_ws, size_t ws_size,
                              hipStream_t stream) {
    const float* x = (const float*)d_in[0];   // [8192, 4096] fp32
    const float* w = (const float*)d_in[1];   // [64, 64, 64] fp32
    float* y = (float*)d_out;                 // [8192, 4096] fp32

    dim3 grid(NROWS / (CHUNK_ROWS * CHUNKS), NBLK);  // (32, 64)
    dim3 block(256);
    StructuredLinearBlocks_kernel<<<grid, block, 0, stream>>>(x, w, y);
}

// Round 4
// 284.250 us; speedup vs baseline: 1.0051x; 1.0051x over previous
//
#include <hip/hip_runtime.h>

// Block-diagonal linear: y[b, n*64+d] = sum_s x[b, n*64+s] * W[n][d][s]
// B = 8192 rows, NB = 64 blocks of 64x64. fp32 in/out, bf16 MFMA internally.
//
// Round-4: round-2 design with the LDS staging-write offset bug fixed
// (bf16 column byte offset is scol*2, NOT scol*4 — the f32-scaled offset
// overran the 128-B row stride, leaving half of each row uninitialized -> NaN).

#define NBLK 64
#define BLKD 64
#define INF 4096
#define NROWS 8192
#define CHUNK_ROWS 64
#define CHUNKS 4

typedef short bf16x8 __attribute__((ext_vector_type(8)));
typedef float f32x4 __attribute__((ext_vector_type(4)));

__device__ inline unsigned short bf_rne(float f) {
    union { float f; unsigned u; } v;
    v.f = f;
    unsigned u = v.u;
    u += 0x7fffu + ((u >> 16) & 1u);   // round-to-nearest-even to bf16
    return (unsigned short)(u >> 16);
}

__device__ inline bf16x8 cvt8(float4 a, float4 b) {
    bf16x8 r;
    r[0] = (short)bf_rne(a.x); r[1] = (short)bf_rne(a.y);
    r[2] = (short)bf_rne(a.z); r[3] = (short)bf_rne(a.w);
    r[4] = (short)bf_rne(b.x); r[5] = (short)bf_rne(b.y);
    r[6] = (short)bf_rne(b.z); r[7] = (short)bf_rne(b.w);
    return r;
}

// LDS byte offset for bf16 tile [64][64] (row stride 128 B), XOR swizzle
// permutes the 8 16-B slots per row so stride-128 fragment reads spread
// across banks (2-way residual = free).
__device__ inline int swz(int row, int colbyte) {
    return row * 128 + (colbyte ^ ((row & 7) << 4));
}

__global__ __launch_bounds__(256) void StructuredLinearBlocks_kernel(
        const float* __restrict__ x, const float* __restrict__ w,
        float* __restrict__ y) {
    __shared__ alignas(16) char lds[16384];   // [0,8K)=W bf16[64][64], [8K,16K)=x tile
    char* wl = lds;
    char* xl = lds + 8192;

    const int tid  = threadIdx.x;
    const int wid  = tid >> 6;
    const int lane = tid & 63;
    const int l15  = lane & 15;
    const int lhi  = lane >> 4;

    const int n = blockIdx.y;
    const float* wn = w + n * (BLKD * BLKD);
    const int row_wg = blockIdx.x * (CHUNK_ROWS * CHUNKS);

    // Staging role: thread handles rows srow and srow+32, 8 f32 at col scol.
    const int srow = tid >> 3;            // 0..31
    const int scol = (tid & 7) * 8;       // f32 column (8 f32 -> 16 B of bf16)
    const int wb0 = swz(srow,      scol * 2);   // bf16 byte offset!
    const int wb1 = swz(srow + 32, scol * 2);

    // ---- Prologue: issue W loads + x-chunk-0 loads (all lane-contiguous) ----
    float4 wr0a, wr0b, wr1a, wr1b;
    {
        const float* p0 = wn + (srow)      * BLKD + scol;
        const float* p1 = wn + (srow + 32) * BLKD + scol;
        wr0a = *(const float4*)p0; wr0b = *(const float4*)(p0 + 4);
        wr1a = *(const float4*)p1; wr1b = *(const float4*)(p1 + 4);
    }
    float4 xr0a, xr0b, xr1a, xr1b;
    {
        const float* p0 = x + (row_wg + srow)      * INF + n * BLKD + scol;
        const float* p1 = x + (row_wg + srow + 32) * INF + n * BLKD + scol;
        xr0a = *(const float4*)p0; xr0b = *(const float4*)(p0 + 4);
        xr1a = *(const float4*)p1; xr1b = *(const float4*)(p1 + 4);
    }
    *(bf16x8*)(wl + wb0) = cvt8(wr0a, wr0b);
    *(bf16x8*)(wl + wb1) = cvt8(wr1a, wr1b);
    *(bf16x8*)(xl + wb0) = cvt8(xr0a, xr0b);
    *(bf16x8*)(xl + wb1) = cvt8(xr1a, xr1b);
    __syncthreads();

    // ---- W fragments (A operand), held in registers for all chunks ----
    // Lane mapping: lane holds M[l15][k], k = h*32 + lhi*8 + e  (byte = k*2).
    bf16x8 bw[4][2];
#pragma unroll
    for (int t = 0; t < 4; ++t) {
#pragma unroll
        for (int h = 0; h < 2; ++h) {
            bw[t][h] = *(const bf16x8*)(wl + swz(t * 16 + l15, h * 64 + lhi * 16));
        }
    }

    // ---- Chunk loop: prefetch c+1 to regs, compute c, then write c+1 to LDS ----
#pragma unroll
    for (int c = 0; c < CHUNKS; ++c) {
        float4 na0, na1, nb0, nb1;
        if (c < CHUNKS - 1) {   // issue BEFORE stores -> vmcnt never waits on stores
            const float* p0 = x + (row_wg + (c + 1) * CHUNK_ROWS + srow)      * INF + n * BLKD + scol;
            const float* p1 = x + (row_wg + (c + 1) * CHUNK_ROWS + srow + 32) * INF + n * BLKD + scol;
            na0 = *(const float4*)p0; na1 = *(const float4*)(p0 + 4);
            nb0 = *(const float4*)p1; nb1 = *(const float4*)(p1 + 4);
        }

        // x fragments (B operand): lane holds x_tile[wid*16 + l15][k].
        bf16x8 xa[2];
#pragma unroll
        for (int h = 0; h < 2; ++h) {
            xa[h] = *(const bf16x8*)(xl + swz(wid * 16 + l15, h * 64 + lhi * 16));
        }

        f32x4 acc[4];
#pragma unroll
        for (int t = 0; t < 4; ++t) {
            acc[t] = (f32x4){0.f, 0.f, 0.f, 0.f};
            acc[t] = __builtin_amdgcn_mfma_f32_16x16x32_bf16(bw[t][0], xa[0], acc[t], 0, 0, 0);
            acc[t] = __builtin_amdgcn_mfma_f32_16x16x32_bf16(bw[t][1], xa[1], acc[t], 0, 0, 0);
        }

        // D = W * x^T: col(l15) = b-row, row(lhi*4+j) = d within tile t
        // -> lane's 4 acc elements are CONSECUTIVE d -> one float4 store per t.
        float* yp = y + (row_wg + c * CHUNK_ROWS + wid * 16 + l15) * INF
                      + n * BLKD + lhi * 4;
#pragma unroll
        for (int t = 0; t < 4; ++t) {
            *(f32x4*)(yp + t * 16) = acc[t];
        }

        if (c < CHUNKS - 1) {
            __syncthreads();   // all waves done reading x tile c
            *(bf16x8*)(xl + wb0) = cvt8(na0, na1);
            *(bf16x8*)(xl + wb1) = cvt8(nb0, nb1);
            __syncthreads();   // x tile c+1 ready
        }
    }
}

extern "C" void kernel_launch(void* const* d_in, const int* in_sizes, int n_in,
                              void* d_out, int out_size, void* d_ws, size_t ws_size,
                              hipStream_t stream) {
    const float* x = (const float*)d_in[0];   // [8192, 4096] fp32
    const float* w = (const float*)d_in[1];   // [64, 64, 64] fp32
    float* y = (float*)d_out;                 // [8192, 4096] fp32

    dim3 grid(NROWS / (CHUNK_ROWS * CHUNKS), NBLK);  // (32, 64)
    dim3 block(256);
    StructuredLinearBlocks_kernel<<<grid, block, 0, stream>>>(x, w, y);
}

// Round 5
// 234.948 us; speedup vs baseline: 1.2161x; 1.2098x over previous
//
#include <hip/hip_runtime.h>

// Block-diagonal linear: y[b, n*64+d] = sum_s x[b, n*64+s] * W[n][d][s]
// B = 8192, NB = 64 blocks of 64x64. fp32 in/out, bf16 MFMA internally.
//
// Round-5: DRAM-granularity redesign. Rounds 1 & 4 both pinned at 1.7 TB/s
// (21% peak) despite opposite instruction patterns -> memory-side page
// locality, caused by the (row-chunk x single-n) WG decomposition touching
// x/y in 256-B strided chunks. New decomposition: WG = 16 rows x 8 n-blocks,
// every global access a >=1-KB contiguous burst:
//   - x panel staged once (1-KB wave-loads), W(n) dbuf (4-KB linear insts),
//   - y transposed through LDS so each store inst = 1 row x 1 KB contiguous.

#define INF 4096
#define NROWS 8192
#define ROWS_WG 16
#define GN 8          // n-blocks per WG

typedef short bf16x8 __attribute__((ext_vector_type(8)));
typedef short bf16x4 __attribute__((ext_vector_type(4)));
typedef float f32x4 __attribute__((ext_vector_type(4)));

__device__ inline unsigned short bf_rne(float f) {
    union { float f; unsigned u; } v; v.f = f;
    unsigned u = v.u;
    u += 0x7fffu + ((u >> 16) & 1u);   // round-to-nearest-even
    return (unsigned short)(u >> 16);
}

__device__ inline bf16x4 cvt4(float4 a) {
    bf16x4 r;
    r[0] = (short)bf_rne(a.x); r[1] = (short)bf_rne(a.y);
    r[2] = (short)bf_rne(a.z); r[3] = (short)bf_rne(a.w);
    return r;
}

// Swizzles: XOR row-bits into the 16-B-slot bits (4..6) of the column byte.
// Same slot-permutation family as round-4 (measured 0 bank conflicts).
__device__ inline int swzx(int row, int colbyte) {   // 1024-B row stride (x panel, ystage)
    return row * 1024 + (colbyte ^ ((row & 7) << 4));
}
__device__ inline int swzw(int row, int colbyte) {   // 128-B row stride (W tiles)
    return row * 128 + (colbyte ^ ((row & 7) << 4));
}

__global__ __launch_bounds__(256, 3) void StructuredLinearBlocks_kernel(
        const float* __restrict__ x, const float* __restrict__ w,
        float* __restrict__ y) {
    __shared__ alignas(16) char lds[49152];
    char* xp   = lds;            // x panel: 16 rows x 512 bf16 (1024 B rows), swizzled
    char* wbuf = lds + 16384;    // W dbuf: 2 x (64 rows x 64 bf16 = 8 KB), swizzled
    char* ys   = lds + 32768;    // y stage: 16 rows x 256 f32 (1024 B rows), swizzled

    const int tid  = threadIdx.x;
    const int wid  = tid >> 6;
    const int lane = tid & 63;
    const int l15  = lane & 15;
    const int lhi  = lane >> 4;

    const int bid = blockIdx.x;
    const int g   = bid & 7;          // n-group (fastest -> same-panel WGs co-stream rows)
    const int p   = bid >> 3;         // row panel
    const int r0  = p * ROWS_WG;
    const int n0  = g * GN;

    // ---- Prologue: stage x panel + W(n0). All loads fully lane-contiguous. ----
    {
        float4 xv[4][2];
        const float* xb = x + (size_t)r0 * INF + n0 * 64;
#pragma unroll
        for (int r = 0; r < 4; ++r) {   // 4 rows per round: wave-inst = 1 row x 1 KB
            const float* pr = xb + (size_t)((tid >> 6) + r * 4) * INF + (tid & 63) * 4;
            xv[r][0] = *(const float4*)pr;
            xv[r][1] = *(const float4*)(pr + 256);
        }
        float4 wv[4];
        const float* pw = w + n0 * 4096 + tid * 4;   // linear: inst = 4 KB contiguous
#pragma unroll
        for (int k = 0; k < 4; ++k) wv[k] = *(const float4*)(pw + k * 1024);

#pragma unroll
        for (int r = 0; r < 4; ++r) {
            int row = (tid >> 6) + r * 4;
            int cb  = (tid & 63) * 8;                 // bf16 byte col
            *(bf16x4*)(xp + swzx(row, cb))       = cvt4(xv[r][0]);
            *(bf16x4*)(xp + swzx(row, cb + 512)) = cvt4(xv[r][1]);
        }
        int wrow = tid >> 4, wcb = (tid & 15) * 8;    // linear idx -> (row, col)
#pragma unroll
        for (int k = 0; k < 4; ++k)
            *(bf16x4*)(wbuf + swzw(wrow + k * 16, wcb)) = cvt4(wv[k]);
    }
    __syncthreads();

    f32x4 acc[4];
#pragma unroll
    for (int i = 0; i < GN; ++i) {
        // Prefetch W(n+1) to regs (issued before anything else this iter).
        float4 wv0, wv1, wv2, wv3;
        if (i < GN - 1) {
            const float* pw = w + (n0 + i + 1) * 4096 + tid * 4;
            wv0 = *(const float4*)pw;
            wv1 = *(const float4*)(pw + 1024);
            wv2 = *(const float4*)(pw + 2048);
            wv3 = *(const float4*)(pw + 3072);
        }

        // Fragments. x: lane holds x[l15][k], k = i*64 + h*32 + lhi*8.
        bf16x8 xa0 = *(const bf16x8*)(xp + swzx(l15, i * 128 + lhi * 16));
        bf16x8 xa1 = *(const bf16x8*)(xp + swzx(l15, i * 128 + 64 + lhi * 16));
        // W: lane holds W[wid*16 + l15][k] from current buffer.
        const char* wc = wbuf + (i & 1) * 8192;
        bf16x8 bw0 = *(const bf16x8*)(wc + swzw(wid * 16 + l15, lhi * 16));
        bf16x8 bw1 = *(const bf16x8*)(wc + swzw(wid * 16 + l15, 64 + lhi * 16));

        f32x4 a = (f32x4){0.f, 0.f, 0.f, 0.f};
        a = __builtin_amdgcn_mfma_f32_16x16x32_bf16(bw0, xa0, a, 0, 0, 0);
        a = __builtin_amdgcn_mfma_f32_16x16x32_bf16(bw1, xa1, a, 0, 0, 0);
        acc[i & 3] = a;   // D: col(l15)=b-row, row(lhi*4+j)=d (within tile wid)

        if ((i & 3) == 3) {
            // Transpose 4 n's of output through ystage -> 1-KB contiguous stores.
#pragma unroll
            for (int j = 0; j < 4; ++j)
                *(f32x4*)(ys + swzx(l15, j * 256 + wid * 64 + lhi * 16)) = acc[j];
            __syncthreads();
            const int gq = i >> 2;
#pragma unroll
            for (int q = 0; q < 4; ++q) {   // wave w streams rows w*4..w*4+3
                int r = wid * 4 + q;
                f32x4 v = *(const f32x4*)(ys + swzx(r, lane * 16));
                *(f32x4*)(y + (size_t)(r0 + r) * INF + (n0 + gq * 4) * 64 + lane * 4) = v;
            }
        }

        if (i < GN - 1) {
            // vmcnt here waits only on the W loads (issued before the stores).
            char* wn = wbuf + ((i + 1) & 1) * 8192;
            int wrow = tid >> 4, wcb = (tid & 15) * 8;
            *(bf16x4*)(wn + swzw(wrow,      wcb)) = cvt4(wv0);
            *(bf16x4*)(wn + swzw(wrow + 16, wcb)) = cvt4(wv1);
            *(bf16x4*)(wn + swzw(wrow + 32, wcb)) = cvt4(wv2);
            *(bf16x4*)(wn + swzw(wrow + 48, wcb)) = cvt4(wv3);
        }
        __syncthreads();
    }
}

extern "C" void kernel_launch(void* const* d_in, const int* in_sizes, int n_in,
                              void* d_out, int out_size, void* d_ws, size_t ws_size,
                              hipStream_t stream) {
    const float* x = (const float*)d_in[0];   // [8192, 4096] fp32
    const float* w = (const float*)d_in[1];   // [64, 64, 64] fp32
    float* y = (float*)d_out;                 // [8192, 4096] fp32

    dim3 grid((NROWS / ROWS_WG) * (64 / GN));  // 512 panels x 8 n-groups = 4096
    dim3 block(256);
    StructuredLinearBlocks_kernel<<<grid, block, 0, stream>>>(x, w, y);
}

// Round 7
// 229.736 us; speedup vs baseline: 1.2437x; 1.0227x over previous
//
#include <hip/hip_runtime.h>

// Block-diagonal linear: y[b, n*64+d] = sum_s x[b, n*64+s] * W[n][d][s]
// B = 8192, 64 blocks of 64x64. fp32 in/out, bf16 MFMA internally.
//
// Round-7: round-6 streaming design, fixed compile error (no LDS pointer
// arrays — buffer selection via offset arithmetic).
//  - WG = 4 n-blocks x stream of 8 row-panels (16 rows each); grid 1024.
//  - W fragments in REGISTERS (loaded once, L2-resident W); no W LDS.
//  - x double-buffered in LDS: panel p+1 loads issued before panel p compute.
//  - y transposed through LDS ystage -> 1-KB contiguous row bursts.

#define INF 4096
#define NROWS 8192
#define RPP 16                  // rows per panel
#define GN 4                    // n-blocks per WG
#define NG 16                   // n-groups = 64/GN
#define NS 64                   // streams per n-group
#define PP ((NROWS / RPP) / NS) // panels per stream = 8

typedef short bf16x8 __attribute__((ext_vector_type(8)));
typedef short bf16x4 __attribute__((ext_vector_type(4)));
typedef float f32x4 __attribute__((ext_vector_type(4)));

__device__ inline unsigned short bf_rne(float f) {
    union { float f; unsigned u; } v; v.f = f;
    unsigned u = v.u;
    u += 0x7fffu + ((u >> 16) & 1u);
    return (unsigned short)(u >> 16);
}

__device__ inline bf16x4 cvt4(float4 a) {
    bf16x4 r;
    r[0] = (short)bf_rne(a.x); r[1] = (short)bf_rne(a.y);
    r[2] = (short)bf_rne(a.z); r[3] = (short)bf_rne(a.w);
    return r;
}

__device__ inline bf16x8 cvt8(float4 a, float4 b) {
    bf16x8 r;
    r[0] = (short)bf_rne(a.x); r[1] = (short)bf_rne(a.y);
    r[2] = (short)bf_rne(a.z); r[3] = (short)bf_rne(a.w);
    r[4] = (short)bf_rne(b.x); r[5] = (short)bf_rne(b.y);
    r[6] = (short)bf_rne(b.z); r[7] = (short)bf_rne(b.w);
    return r;
}

// x tile: [16][256] bf16, 512-B rows. ystage: [16][256] f32, 1024-B rows.
// XOR of row bits into byte bits 4..6 permutes 16-B slots (2-way residual = free).
__device__ inline int swzx(int row, int cb) { return row * 512  + (cb ^ ((row & 7) << 4)); }
__device__ inline int swzy(int row, int cb) { return row * 1024 + (cb ^ ((row & 7) << 4)); }

__global__ __launch_bounds__(256, 4) void StructuredLinearBlocks_kernel(
        const float* __restrict__ x, const float* __restrict__ w,
        float* __restrict__ y) {
    __shared__ alignas(16) char lds[32768];
    char* ys = lds + 16384;                // y transpose stage (f32)

    const int tid  = threadIdx.x;
    const int wid  = tid >> 6;
    const int lane = tid & 63;
    const int l15  = lane & 15;
    const int lhi  = lane >> 4;

    const int bid = blockIdx.x;
    const int g   = bid & (NG - 1);   // n-group: 16 consecutive bids cover full rows
    const int s   = bid >> 4;         // stream id
    const int c0  = g * (GN * 64);    // f32 column offset of this n-group

    // ---- W fragments once, straight from global (L2-resident, 1 MB total).
    // Lane mapping matches LDS-path frags: lane holds W[n][wid*16+l15][k],
    // k = h*32 + lhi*8 + e -> 8 consecutive f32 per lane.
    bf16x8 bw[GN][2];
#pragma unroll
    for (int n = 0; n < GN; ++n) {
#pragma unroll
        for (int h = 0; h < 2; ++h) {
            const float* p = w + (size_t)(g * GN + n) * 4096
                               + (wid * 16 + l15) * 64 + h * 32 + lhi * 8;
            bw[n][h] = cvt8(*(const float4*)p, *(const float4*)(p + 4));
        }
    }

    // ---- Panel 0: load (1-KB bursts: one row per wave-inst), cvt, stage.
    float4 xv[4];
#pragma unroll
    for (int r = 0; r < 4; ++r) {
        const size_t row = (size_t)s * RPP + r * 4 + wid;
        xv[r] = *(const float4*)(x + row * INF + c0 + lane * 4);
    }
#pragma unroll
    for (int r = 0; r < 4; ++r)
        *(bf16x4*)(lds + swzx(r * 4 + wid, lane * 8)) = cvt4(xv[r]);
    __syncthreads();

#pragma unroll 1
    for (int it = 0; it < PP; ++it) {
        char* cur = lds + (it & 1) * 8192;
        char* nxt = lds + ((it + 1) & 1) * 8192;

        // 1. Issue next panel's x loads FIRST (in flight through everything below).
        if (it + 1 < PP) {
#pragma unroll
            for (int r = 0; r < 4; ++r) {
                const size_t row = (size_t)((it + 1) * NS + s) * RPP + r * 4 + wid;
                xv[r] = *(const float4*)(x + row * INF + c0 + lane * 4);
            }
        }

        // 2. Compute: per n-block, 2 MFMAs. x frag: lane = x_panel[l15][k].
        f32x4 acc[GN];
#pragma unroll
        for (int n = 0; n < GN; ++n) {
            bf16x8 xa0 = *(const bf16x8*)(cur + swzx(l15, n * 128 + lhi * 16));
            bf16x8 xa1 = *(const bf16x8*)(cur + swzx(l15, n * 128 + 64 + lhi * 16));
            f32x4 a = (f32x4){0.f, 0.f, 0.f, 0.f};
            a = __builtin_amdgcn_mfma_f32_16x16x32_bf16(bw[n][0], xa0, a, 0, 0, 0);
            a = __builtin_amdgcn_mfma_f32_16x16x32_bf16(bw[n][1], xa1, a, 0, 0, 0);
            acc[n] = a;
        }

        // 3. Transpose through ystage -> 1-KB contiguous y row bursts.
        __syncthreads();   // prev panel's ystage reads complete
#pragma unroll
        for (int n = 0; n < GN; ++n)   // D: col(l15)=b-row, row(lhi*4+j)=d
            *(f32x4*)(ys + swzy(l15, n * 256 + wid * 64 + lhi * 16)) = acc[n];
        __syncthreads();
        const size_t r0 = (size_t)(it * NS + s) * RPP;
#pragma unroll
        for (int q = 0; q < 4; ++q) {
            const int r = wid * 4 + q;
            f32x4 v = *(const f32x4*)(ys + swzy(r, lane * 16));
            *(f32x4*)(y + (r0 + r) * INF + c0 + lane * 4) = v;
        }

        // 4. Stage next panel (vmcnt wait lands here, after stores issued).
        if (it + 1 < PP) {
#pragma unroll
            for (int r = 0; r < 4; ++r)
                *(bf16x4*)(nxt + swzx(r * 4 + wid, lane * 8)) = cvt4(xv[r]);
        }
        __syncthreads();
    }
}

extern "C" void kernel_launch(void* const* d_in, const int* in_sizes, int n_in,
                              void* d_out, int out_size, void* d_ws, size_t ws_size,
                              hipStream_t stream) {
    const float* x = (const float*)d_in[0];   // [8192, 4096] fp32
    const float* w = (const float*)d_in[1];   // [64, 64, 64] fp32
    float* y = (float*)d_out;                 // [8192, 4096] fp32

    dim3 grid(NG * NS);   // 1024
    dim3 block(256);
    StructuredLinearBlocks_kernel<<<grid, block, 0, stream>>>(x, w, y);
}